// Round 1
// baseline (5057.598 us; speedup 1.0000x reference)
//
#include <hip/hip_runtime.h>
#include <hip/hip_bf16.h>

// ---------------------------------------------------------------------------
// MultiheadAttention block (B=4, L=2048, D=2048, H=1), fp32 baseline.
//   y    = LN( (ctx @ Wo + bo) + q_proj[b, 0, :] ) * g + b
//   attn = softmax(q_proj @ k_proj^T / sqrt(D))
// d_out = [ y (B*L*D) | attn (B*L*L) ] fp32.
// Round-0 strategy: correctness-first fp32 VALU GEMMs (no fp32 MFMA on CDNA4).
// Next rounds: split-bf16 MFMA GEMMs once tolerance is confirmed.
// ---------------------------------------------------------------------------

#define TILE 128
#define BK   16
#define PADF 4   // +4 floats keeps 16B alignment of rows (132*4 = 528 = 33*16)

constexpr int   kB   = 4;
constexpr int   kL   = 2048;
constexpr int   kD   = 2048;
constexpr float kScale = 0.022097086912079608f;  // 1/sqrt(2048)
constexpr float kEps   = 1e-6f;

// C[M,N] = A[M,K] @ (BT ? B^T : B) * scale (+ bias), batched via blockIdx.z.
// A row-major ldA=K. B: BT ? [N,K] row-major : [K,N] row-major. C row-major ldC=N.
template<bool BT, bool BIAS>
__global__ __launch_bounds__(256)
void gemm128(const float* __restrict__ A, const float* __restrict__ B,
             const float* __restrict__ bias, float* __restrict__ C,
             int M, int N, int K, long sA, long sB, long sC, float scale)
{
    __shared__ float As[BK][TILE + PADF];
    __shared__ float Bs[BK][TILE + PADF];

    const int tid = threadIdx.x;
    const int tx  = tid & 15;
    const int ty  = tid >> 4;
    const int m0  = blockIdx.y * TILE;
    const int n0  = blockIdx.x * TILE;

    const float* Ab = A + (size_t)blockIdx.z * sA;
    const float* Bb = B + (size_t)blockIdx.z * sB;
    float*       Cb = C + (size_t)blockIdx.z * sC;

    float acc[8][8];
#pragma unroll
    for (int r = 0; r < 8; ++r)
#pragma unroll
        for (int c = 0; c < 8; ++c) acc[r][c] = 0.f;

    for (int kt = 0; kt < K; kt += BK) {
        // --- stage A tile, transposed: As[k][row] ---
#pragma unroll
        for (int i = 0; i < 2; ++i) {
            int f   = tid + i * 256;          // 0..511
            int row = f >> 2;                 // 0..127
            int kq  = (f & 3) * 4;            // 0,4,8,12
            float4 v = *(const float4*)(Ab + (size_t)(m0 + row) * K + kt + kq);
            As[kq + 0][row] = v.x;
            As[kq + 1][row] = v.y;
            As[kq + 2][row] = v.z;
            As[kq + 3][row] = v.w;
        }
        // --- stage B tile: Bs[k][col] ---
        if (BT) {
#pragma unroll
            for (int i = 0; i < 2; ++i) {
                int f   = tid + i * 256;
                int row = f >> 2;
                int kq  = (f & 3) * 4;
                float4 v = *(const float4*)(Bb + (size_t)(n0 + row) * K + kt + kq);
                Bs[kq + 0][row] = v.x;
                Bs[kq + 1][row] = v.y;
                Bs[kq + 2][row] = v.z;
                Bs[kq + 3][row] = v.w;
            }
        } else {
#pragma unroll
            for (int i = 0; i < 2; ++i) {
                int f  = tid + i * 256;
                int kk = f >> 5;              // 0..15
                int nq = (f & 31) * 4;        // 0..124
                float4 v = *(const float4*)(Bb + (size_t)(kt + kk) * N + n0 + nq);
                *(float4*)&Bs[kk][nq] = v;
            }
        }
        __syncthreads();

#pragma unroll
        for (int kk = 0; kk < BK; ++kk) {
            float4 a0 = *(const float4*)&As[kk][ty * 4];
            float4 a1 = *(const float4*)&As[kk][ty * 4 + 64];
            float4 b0 = *(const float4*)&Bs[kk][tx * 4];
            float4 b1 = *(const float4*)&Bs[kk][tx * 4 + 64];
            float ar[8] = {a0.x, a0.y, a0.z, a0.w, a1.x, a1.y, a1.z, a1.w};
            float br[8] = {b0.x, b0.y, b0.z, b0.w, b1.x, b1.y, b1.z, b1.w};
#pragma unroll
            for (int r = 0; r < 8; ++r)
#pragma unroll
                for (int c = 0; c < 8; ++c)
                    acc[r][c] = fmaf(ar[r], br[c], acc[r][c]);
        }
        __syncthreads();
    }

    // --- epilogue: scale, +bias, store float4 ---
    float bv[8];
#pragma unroll
    for (int c = 0; c < 8; ++c)
        bv[c] = BIAS ? bias[n0 + tx * 4 + (c & 3) + ((c >> 2) << 6)] : 0.f;

#pragma unroll
    for (int r = 0; r < 8; ++r) {
        int grow = m0 + ty * 4 + (r & 3) + ((r >> 2) << 6);
        float* crow = Cb + (size_t)grow * N + n0;
#pragma unroll
        for (int j = 0; j < 2; ++j) {
            float4 o;
            o.x = acc[r][j * 4 + 0] * scale + bv[j * 4 + 0];
            o.y = acc[r][j * 4 + 1] * scale + bv[j * 4 + 1];
            o.z = acc[r][j * 4 + 2] * scale + bv[j * 4 + 2];
            o.w = acc[r][j * 4 + 3] * scale + bv[j * 4 + 3];
            *(float4*)(crow + tx * 4 + j * 64) = o;
        }
    }
}

// In-place row softmax over rows of length kL (one block per row).
__global__ __launch_bounds__(256)
void softmax_rows(float* __restrict__ attn)
{
    const size_t base = (size_t)blockIdx.x * kL;
    const int tid  = threadIdx.x;
    const int lane = tid & 63;
    const int wid  = tid >> 6;

    float4 v0 = *(const float4*)(attn + base + tid * 8);
    float4 v1 = *(const float4*)(attn + base + tid * 8 + 4);
    float x[8] = {v0.x, v0.y, v0.z, v0.w, v1.x, v1.y, v1.z, v1.w};

    float m = x[0];
#pragma unroll
    for (int i = 1; i < 8; ++i) m = fmaxf(m, x[i]);
#pragma unroll
    for (int o = 32; o > 0; o >>= 1) m = fmaxf(m, __shfl_xor(m, o));

    __shared__ float rb[8];
    if (lane == 0) rb[wid] = m;
    __syncthreads();
    m = fmaxf(fmaxf(rb[0], rb[1]), fmaxf(rb[2], rb[3]));

    float s = 0.f;
#pragma unroll
    for (int i = 0; i < 8; ++i) { x[i] = __expf(x[i] - m); s += x[i]; }
#pragma unroll
    for (int o = 32; o > 0; o >>= 1) s += __shfl_xor(s, o);
    if (lane == 0) rb[4 + wid] = s;
    __syncthreads();
    s = rb[4] + rb[5] + rb[6] + rb[7];

    float inv = 1.0f / s;
    float4 o0 = {x[0] * inv, x[1] * inv, x[2] * inv, x[3] * inv};
    float4 o1 = {x[4] * inv, x[5] * inv, x[6] * inv, x[7] * inv};
    *(float4*)(attn + base + tid * 8)     = o0;
    *(float4*)(attn + base + tid * 8 + 4) = o1;
}

// resid = outp[row] + q_proj[batch, 0, :]; y = LN(resid)*g + b. One block/row.
__global__ __launch_bounds__(256)
void resid_ln(const float* __restrict__ outp, const float* __restrict__ qp,
              const float* __restrict__ g, const float* __restrict__ bet,
              float* __restrict__ y)
{
    const int row = blockIdx.x;
    const int b   = row >> 11;                   // row / kL
    const size_t ob = (size_t)row * kD;
    const size_t qb = (size_t)b * kL * kD;       // q_proj row 0 of batch b
    const int tid  = threadIdx.x;
    const int lane = tid & 63;
    const int wid  = tid >> 6;

    float4 a0 = *(const float4*)(outp + ob + tid * 8);
    float4 a1 = *(const float4*)(outp + ob + tid * 8 + 4);
    float4 q0 = *(const float4*)(qp + qb + tid * 8);
    float4 q1 = *(const float4*)(qp + qb + tid * 8 + 4);
    float x[8] = {a0.x + q0.x, a0.y + q0.y, a0.z + q0.z, a0.w + q0.w,
                  a1.x + q1.x, a1.y + q1.y, a1.z + q1.z, a1.w + q1.w};

    float s = 0.f, ss = 0.f;
#pragma unroll
    for (int i = 0; i < 8; ++i) { s += x[i]; ss += x[i] * x[i]; }
#pragma unroll
    for (int o = 32; o > 0; o >>= 1) {
        s  += __shfl_xor(s, o);
        ss += __shfl_xor(ss, o);
    }
    __shared__ float rb[16];
    if (lane == 0) { rb[wid] = s; rb[8 + wid] = ss; }
    __syncthreads();
    s  = rb[0] + rb[1] + rb[2] + rb[3];
    ss = rb[8] + rb[9] + rb[10] + rb[11];

    const float mu  = s * (1.0f / kD);
    const float var = ss * (1.0f / kD) - mu * mu;
    const float rs  = rsqrtf(var + kEps);

    float4 g0 = *(const float4*)(g + tid * 8);
    float4 g1 = *(const float4*)(g + tid * 8 + 4);
    float4 b0 = *(const float4*)(bet + tid * 8);
    float4 b1 = *(const float4*)(bet + tid * 8 + 4);

    float4 o0, o1;
    o0.x = (x[0] - mu) * rs * g0.x + b0.x;
    o0.y = (x[1] - mu) * rs * g0.y + b0.y;
    o0.z = (x[2] - mu) * rs * g0.z + b0.z;
    o0.w = (x[3] - mu) * rs * g0.w + b0.w;
    o1.x = (x[4] - mu) * rs * g1.x + b1.x;
    o1.y = (x[5] - mu) * rs * g1.y + b1.y;
    o1.z = (x[6] - mu) * rs * g1.z + b1.z;
    o1.w = (x[7] - mu) * rs * g1.w + b1.w;
    *(float4*)(y + ob + tid * 8)     = o0;
    *(float4*)(y + ob + tid * 8 + 4) = o1;
}

extern "C" void kernel_launch(void* const* d_in, const int* in_sizes, int n_in,
                              void* d_out, int out_size, void* d_ws, size_t ws_size,
                              hipStream_t stream)
{
    (void)in_sizes; (void)n_in; (void)out_size; (void)ws_size;

    const float* q_in = (const float*)d_in[0];
    const float* k_in = (const float*)d_in[1];
    const float* v_in = (const float*)d_in[2];
    const float* wq_w = (const float*)d_in[3];
    const float* wq_b = (const float*)d_in[4];
    const float* wk_w = (const float*)d_in[5];
    const float* wk_b = (const float*)d_in[6];
    const float* wv_w = (const float*)d_in[7];
    const float* wv_b = (const float*)d_in[8];
    const float* wo_w = (const float*)d_in[9];
    const float* wo_b = (const float*)d_in[10];
    const float* ln_g = (const float*)d_in[11];
    const float* ln_b = (const float*)d_in[12];

    const size_t NE = (size_t)kB * kL * kD;      // 16,777,216
    float* y_out = (float*)d_out;                // [B,L,D]
    float* attn  = (float*)d_out + NE;           // [B,L,L]

    float* q    = (float*)d_ws;                  // [B*L, D]
    float* k    = q + NE;
    float* v    = k + NE;
    float* ctx  = k;                             // k dead after logits GEMM
    float* outp = v;                             // v dead after ctx GEMM

    const dim3 blk(256);
    const int  M = kB * kL;                      // 8192
    const long sLD = (long)kL * kD;
    const long sLL = (long)kL * kL;

    // q/k/v projections: [8192,2048] @ [2048,2048] + bias
    gemm128<false, true><<<dim3(kD / TILE, M / TILE, 1), blk, 0, stream>>>(
        q_in, wq_w, wq_b, q, M, kD, kD, 0, 0, 0, 1.0f);
    gemm128<false, true><<<dim3(kD / TILE, M / TILE, 1), blk, 0, stream>>>(
        k_in, wk_w, wk_b, k, M, kD, kD, 0, 0, 0, 1.0f);
    gemm128<false, true><<<dim3(kD / TILE, M / TILE, 1), blk, 0, stream>>>(
        v_in, wv_w, wv_b, v, M, kD, kD, 0, 0, 0, 1.0f);

    // logits = q @ k^T * scale, per batch, straight into d_out attn region
    gemm128<true, false><<<dim3(kL / TILE, kL / TILE, kB), blk, 0, stream>>>(
        q, k, nullptr, attn, kL, kL, kD, sLD, sLD, sLL, kScale);

    softmax_rows<<<dim3(kB * kL), blk, 0, stream>>>(attn);

    // ctx = attn @ v, per batch
    gemm128<false, false><<<dim3(kD / TILE, kL / TILE, kB), blk, 0, stream>>>(
        attn, v, nullptr, ctx, kL, kD, kL, sLL, sLD, sLD, 1.0f);

    // out = ctx @ wo + bo
    gemm128<false, true><<<dim3(kD / TILE, M / TILE, 1), blk, 0, stream>>>(
        ctx, wo_w, wo_b, outp, M, kD, kD, 0, 0, 0, 1.0f);

    // y = LN(out + q_proj[b,0,:]) * g + b
    resid_ln<<<dim3(kB * kL), blk, 0, stream>>>(outp, q, ln_g, ln_b, y_out);
}

// Round 5
// 1638.967 us; speedup vs baseline: 3.0858x; 3.0858x over previous
//
#include <hip/hip_runtime.h>
#include <hip/hip_bf16.h>
#include <stdint.h>

// ---------------------------------------------------------------------------
// MultiheadAttention block (B=4, L=2048, D=2048, H=1).
// Split-bf16 (bf16x3) MFMA GEMMs: A*B ~= Ahi*Bhi + Ahi*Blo + Alo*Bhi.
// 128x128 tile, BK=32, 4 waves, mfma_f32_16x16x32_bf16, global_load_lds w=16.
// Scratch overlay keeps d_ws usage at ~201.4MB (proven in round 0):
//   - wq/wk/wv transposed hi/lo planes live in d_out's attn region (dead
//     until the logits GEMM overwrites it)
//   - wo transposed hi/lo planes live in slotA (dead after ctx GEMM)
// ---------------------------------------------------------------------------

typedef __bf16 bf16x8 __attribute__((ext_vector_type(8)));
typedef __bf16 bf16x4 __attribute__((ext_vector_type(4)));
typedef float  floatx4 __attribute__((ext_vector_type(4)));

constexpr int    kB = 4, kL = 2048, kD = 2048;
constexpr float  kScale = 0.022097086912079608f;  // 1/sqrt(2048)
constexpr float  kEps   = 1e-6f;
constexpr size_t kNE = (size_t)kB * kL * kD;      // 16,777,216
constexpr size_t kNW = (size_t)kD * kD;           // 4,194,304
constexpr long   kSB = 4194304;                   // per-batch stride (L*D == L*L)

__device__ __forceinline__ void gll16(const void* g, void* l) {
    __builtin_amdgcn_global_load_lds(
        (__attribute__((address_space(1))) void*)(void*)g,
        (__attribute__((address_space(3))) void*)l, 16, 0, 0);
}

struct bfpair { __bf16 h, l; };
__device__ __forceinline__ bfpair split_bf16(float x) {
    bfpair p;
    p.h = (__bf16)x;
    p.l = (__bf16)(x - (float)p.h);
    return p;
}

// C = A @ B'^T (*scale, +bias). A: [M,K] as fp32 (CONVA) or bf16 hi/lo planes.
// B': [N,K] bf16 hi/lo planes. Output: fp32 (WF32) and/or bf16 hi/lo (WHL).
template<bool CONVA, bool BIAS, bool WF32, bool WHL>
__global__ __launch_bounds__(256)
void gemm_hl(const float* __restrict__ Af,
             const __bf16* __restrict__ Ah, const __bf16* __restrict__ Al,
             const __bf16* __restrict__ Bh, const __bf16* __restrict__ Bl,
             const float* __restrict__ bias,
             float* __restrict__ Cf, __bf16* __restrict__ Ch, __bf16* __restrict__ Cl,
             int M, int N, int K, long sA, long sB, long sC, float scale)
{
    __shared__ __bf16 sAh[128 * 32], sAl[128 * 32];
    __shared__ __bf16 sBh[128 * 32], sBl[128 * 32];

    const int tid  = threadIdx.x;
    const int lane = tid & 63;
    const int wid  = tid >> 6;
    const int wr   = wid >> 1, wc = wid & 1;     // 2x2 waves, 64x64 each
    const int m0   = blockIdx.y * 128, n0 = blockIdx.x * 128;

    const size_t aoff = (size_t)blockIdx.z * sA;
    const size_t boff = (size_t)blockIdx.z * sB;
    const size_t coff = (size_t)blockIdx.z * sC;

    floatx4 acc[4][4];
#pragma unroll
    for (int m = 0; m < 4; ++m)
#pragma unroll
        for (int n = 0; n < 4; ++n) acc[m][n] = floatx4{0.f, 0.f, 0.f, 0.f};

    // fragment read offsets (elements) in [128][32] row-major planes
    const int frow  = lane & 15;
    const int kblk  = lane >> 4;
    const int aBase = (wr * 64 + frow) * 32 + kblk * 8;
    const int bBase = (wc * 64 + frow) * 32 + kblk * 8;
    // global_load_lds per-lane source mapping (16 rows x 64B per instruction)
    const int srow = lane >> 2;
    const int scol = (lane & 3) * 8;

    for (int kt = 0; kt < K; kt += 32) {
        if constexpr (CONVA) {
            // fp32 A rows wid*32..+31 -> hi/lo in LDS
#pragma unroll
            for (int j = 0; j < 4; ++j) {
                int flat = j * 64 + lane;
                int r  = wid * 32 + (flat >> 3);
                int kq = (flat & 7) * 4;
                float4 v = *(const float4*)(Af + aoff + (size_t)(m0 + r) * K + kt + kq);
                bf16x4 hv, lv;
                bfpair p0 = split_bf16(v.x); hv[0] = p0.h; lv[0] = p0.l;
                bfpair p1 = split_bf16(v.y); hv[1] = p1.h; lv[1] = p1.l;
                bfpair p2 = split_bf16(v.z); hv[2] = p2.h; lv[2] = p2.l;
                bfpair p3 = split_bf16(v.w); hv[3] = p3.h; lv[3] = p3.l;
                *(bf16x4*)&sAh[r * 32 + kq] = hv;
                *(bf16x4*)&sAl[r * 32 + kq] = lv;
            }
        } else {
#pragma unroll
            for (int i = 0; i < 2; ++i) {
                int rb = wid * 32 + i * 16;
                gll16(Ah + aoff + (size_t)(m0 + rb + srow) * K + kt + scol, &sAh[rb * 32]);
                gll16(Al + aoff + (size_t)(m0 + rb + srow) * K + kt + scol, &sAl[rb * 32]);
            }
        }
#pragma unroll
        for (int i = 0; i < 2; ++i) {
            int rb = wid * 32 + i * 16;
            gll16(Bh + boff + (size_t)(n0 + rb + srow) * K + kt + scol, &sBh[rb * 32]);
            gll16(Bl + boff + (size_t)(n0 + rb + srow) * K + kt + scol, &sBl[rb * 32]);
        }
        __syncthreads();

        bf16x8 ah_[4], al_[4], bh_[4], bl_[4];
#pragma unroll
        for (int m = 0; m < 4; ++m) {
            ah_[m] = *(const bf16x8*)&sAh[aBase + m * 512];
            al_[m] = *(const bf16x8*)&sAl[aBase + m * 512];
        }
#pragma unroll
        for (int n = 0; n < 4; ++n) {
            bh_[n] = *(const bf16x8*)&sBh[bBase + n * 512];
            bl_[n] = *(const bf16x8*)&sBl[bBase + n * 512];
        }
#pragma unroll
        for (int m = 0; m < 4; ++m)
#pragma unroll
            for (int n = 0; n < 4; ++n) {
                acc[m][n] = __builtin_amdgcn_mfma_f32_16x16x32_bf16(ah_[m], bh_[n], acc[m][n], 0, 0, 0);
                acc[m][n] = __builtin_amdgcn_mfma_f32_16x16x32_bf16(ah_[m], bl_[n], acc[m][n], 0, 0, 0);
                acc[m][n] = __builtin_amdgcn_mfma_f32_16x16x32_bf16(al_[m], bh_[n], acc[m][n], 0, 0, 0);
            }
        __syncthreads();
    }

    // epilogue: C/D layout col = lane&15, row = (lane>>4)*4 + reg
    const int crow0 = m0 + wr * 64 + ((lane >> 4) << 2);
    const int ccol0 = n0 + wc * 64 + (lane & 15);
#pragma unroll
    for (int n = 0; n < 4; ++n) {
        const int col = ccol0 + n * 16;
        const float bv = BIAS ? bias[col] : 0.f;
#pragma unroll
        for (int m = 0; m < 4; ++m)
#pragma unroll
            for (int j = 0; j < 4; ++j) {
                const size_t idx = coff + (size_t)(crow0 + m * 16 + j) * N + col;
                const float x = acc[m][n][j] * scale + bv;
                if constexpr (WF32) Cf[idx] = x;
                if constexpr (WHL) {
                    bfpair p = split_bf16(x);
                    Ch[idx] = p.h; Cl[idx] = p.l;
                }
            }
    }
}

// W[K=2048][N=2048] fp32 -> WT hi/lo [N][K] bf16 (64x64 LDS tile transpose)
__global__ __launch_bounds__(256)
void convert_wT(const float* __restrict__ w, __bf16* __restrict__ th, __bf16* __restrict__ tl)
{
    __shared__ float t[64][65];
    const int tid = threadIdx.x;
    const int r0 = blockIdx.y * 64, c0 = blockIdx.x * 64;
#pragma unroll
    for (int i = 0; i < 4; ++i) {
        int flat = i * 256 + tid;
        int r = flat >> 4, c4 = (flat & 15) * 4;
        float4 v = *(const float4*)(w + (size_t)(r0 + r) * kD + c0 + c4);
        t[r][c4 + 0] = v.x; t[r][c4 + 1] = v.y; t[r][c4 + 2] = v.z; t[r][c4 + 3] = v.w;
    }
    __syncthreads();
#pragma unroll
    for (int i = 0; i < 4; ++i) {
        int flat = i * 256 + tid;
        int c = flat >> 4, r4 = (flat & 15) * 4;
        bf16x4 hv, lv;
#pragma unroll
        for (int j = 0; j < 4; ++j) {
            bfpair p = split_bf16(t[r4 + j][c]);
            hv[j] = p.h; lv[j] = p.l;
        }
        *(bf16x4*)&th[(size_t)(c0 + c) * kD + r0 + r4] = hv;
        *(bf16x4*)&tl[(size_t)(c0 + c) * kD + r0 + r4] = lv;
    }
}

// per-batch transpose of hi/lo planes: v[b][l][d] -> vT[b][d][l]
__global__ __launch_bounds__(256)
void transpose_hl(const __bf16* __restrict__ sh, const __bf16* __restrict__ sl,
                  __bf16* __restrict__ dh, __bf16* __restrict__ dl)
{
    __shared__ __bf16 t[64][73];   // 73: breaks pow-2 column stride (bank conflicts)
    const int b  = blockIdx.z >> 1;
    const bool lo = blockIdx.z & 1;
    const __bf16* src = (lo ? sl : sh) + (size_t)b * kSB;
    __bf16*       dst = (lo ? dl : dh) + (size_t)b * kSB;
    const int tid = threadIdx.x;
    const int r0 = blockIdx.y * 64, c0 = blockIdx.x * 64;
#pragma unroll
    for (int i = 0; i < 2; ++i) {
        int flat = i * 256 + tid;
        int r = flat >> 3, c8 = (flat & 7) * 8;
        bf16x8 v = *(const bf16x8*)&src[(size_t)(r0 + r) * kD + c0 + c8];
#pragma unroll
        for (int j = 0; j < 8; ++j) t[r][c8 + j] = v[j];
    }
    __syncthreads();
#pragma unroll
    for (int i = 0; i < 2; ++i) {
        int flat = i * 256 + tid;
        int c = flat >> 3, r8 = (flat & 7) * 8;
        bf16x8 v;
#pragma unroll
        for (int j = 0; j < 8; ++j) v[j] = t[r8 + j][c];
        *(bf16x8*)&dst[(size_t)(c0 + c) * kL + r0 + r8] = v;
    }
}

// in-place row softmax + bf16 hi/lo output planes. One block per row.
__global__ __launch_bounds__(256)
void softmax_rows(float* __restrict__ attn, __bf16* __restrict__ oh, __bf16* __restrict__ ol)
{
    const size_t base = (size_t)blockIdx.x * kL;
    const int tid = threadIdx.x, lane = tid & 63, wid = tid >> 6;

    float4 v0 = *(const float4*)(attn + base + tid * 8);
    float4 v1 = *(const float4*)(attn + base + tid * 8 + 4);
    float x[8] = {v0.x, v0.y, v0.z, v0.w, v1.x, v1.y, v1.z, v1.w};

    float m = x[0];
#pragma unroll
    for (int i = 1; i < 8; ++i) m = fmaxf(m, x[i]);
#pragma unroll
    for (int o = 32; o > 0; o >>= 1) m = fmaxf(m, __shfl_xor(m, o));

    __shared__ float rb[8];
    if (lane == 0) rb[wid] = m;
    __syncthreads();
    m = fmaxf(fmaxf(rb[0], rb[1]), fmaxf(rb[2], rb[3]));

    float s = 0.f;
#pragma unroll
    for (int i = 0; i < 8; ++i) { x[i] = __expf(x[i] - m); s += x[i]; }
#pragma unroll
    for (int o = 32; o > 0; o >>= 1) s += __shfl_xor(s, o);
    if (lane == 0) rb[4 + wid] = s;
    __syncthreads();
    s = rb[4] + rb[5] + rb[6] + rb[7];

    const float inv = 1.0f / s;
    bf16x8 hv, lv;
#pragma unroll
    for (int i = 0; i < 8; ++i) {
        x[i] *= inv;
        bfpair p = split_bf16(x[i]);
        hv[i] = p.h; lv[i] = p.l;
    }
    float4 o0 = {x[0], x[1], x[2], x[3]};
    float4 o1 = {x[4], x[5], x[6], x[7]};
    *(float4*)(attn + base + tid * 8)     = o0;
    *(float4*)(attn + base + tid * 8 + 4) = o1;
    *(bf16x8*)&oh[base + tid * 8] = hv;
    *(bf16x8*)&ol[base + tid * 8] = lv;
}

// q_proj row 0 of each batch (hi+lo) -> fp32 [4][2048]
__global__ __launch_bounds__(256)
void copy_qrow0(const __bf16* __restrict__ qh, const __bf16* __restrict__ ql,
                float* __restrict__ q0)
{
    const int idx = blockIdx.x * 256 + threadIdx.x;   // 0..8191
    const int b = idx >> 11, d = idx & 2047;
    const size_t off = (size_t)b * kSB + d;
    q0[idx] = (float)qh[off] + (float)ql[off];
}

// in-place: y = LN(y + qrow0[b]) * g + b
__global__ __launch_bounds__(256)
void resid_ln(float* __restrict__ y, const float* __restrict__ q0,
              const float* __restrict__ g, const float* __restrict__ bet)
{
    const int row = blockIdx.x;
    const int b = row >> 11;
    const size_t ob = (size_t)row * kD;
    const int tid = threadIdx.x, lane = tid & 63, wid = tid >> 6;

    float4 a0 = *(const float4*)(y + ob + tid * 8);
    float4 a1 = *(const float4*)(y + ob + tid * 8 + 4);
    float4 q0v = *(const float4*)(q0 + b * 2048 + tid * 8);
    float4 q1v = *(const float4*)(q0 + b * 2048 + tid * 8 + 4);
    float x[8] = {a0.x + q0v.x, a0.y + q0v.y, a0.z + q0v.z, a0.w + q0v.w,
                  a1.x + q1v.x, a1.y + q1v.y, a1.z + q1v.z, a1.w + q1v.w};

    float s = 0.f, ss = 0.f;
#pragma unroll
    for (int i = 0; i < 8; ++i) { s += x[i]; ss += x[i] * x[i]; }
#pragma unroll
    for (int o = 32; o > 0; o >>= 1) { s += __shfl_xor(s, o); ss += __shfl_xor(ss, o); }
    __shared__ float rb[16];
    if (lane == 0) { rb[wid] = s; rb[8 + wid] = ss; }
    __syncthreads();
    s  = rb[0] + rb[1] + rb[2] + rb[3];
    ss = rb[8] + rb[9] + rb[10] + rb[11];

    const float mu  = s * (1.0f / kD);
    const float var = ss * (1.0f / kD) - mu * mu;
    const float rs  = rsqrtf(var + kEps);

    float4 g0 = *(const float4*)(g + tid * 8);
    float4 g1 = *(const float4*)(g + tid * 8 + 4);
    float4 b0 = *(const float4*)(bet + tid * 8);
    float4 b1 = *(const float4*)(bet + tid * 8 + 4);

    float4 o0, o1;
    o0.x = (x[0] - mu) * rs * g0.x + b0.x;
    o0.y = (x[1] - mu) * rs * g0.y + b0.y;
    o0.z = (x[2] - mu) * rs * g0.z + b0.z;
    o0.w = (x[3] - mu) * rs * g0.w + b0.w;
    o1.x = (x[4] - mu) * rs * g1.x + b1.x;
    o1.y = (x[5] - mu) * rs * g1.y + b1.y;
    o1.z = (x[6] - mu) * rs * g1.z + b1.z;
    o1.w = (x[7] - mu) * rs * g1.w + b1.w;
    *(float4*)(y + ob + tid * 8)     = o0;
    *(float4*)(y + ob + tid * 8 + 4) = o1;
}

extern "C" void kernel_launch(void* const* d_in, const int* in_sizes, int n_in,
                              void* d_out, int out_size, void* d_ws, size_t ws_size,
                              hipStream_t stream)
{
    (void)in_sizes; (void)n_in; (void)out_size; (void)ws_size;

    const float* q_in = (const float*)d_in[0];
    const float* k_in = (const float*)d_in[1];
    const float* v_in = (const float*)d_in[2];
    const float* wq_w = (const float*)d_in[3];
    const float* wq_b = (const float*)d_in[4];
    const float* wk_w = (const float*)d_in[5];
    const float* wk_b = (const float*)d_in[6];
    const float* wv_w = (const float*)d_in[7];
    const float* wv_b = (const float*)d_in[8];
    const float* wo_w = (const float*)d_in[9];
    const float* wo_b = (const float*)d_in[10];
    const float* ln_g = (const float*)d_in[11];
    const float* ln_b = (const float*)d_in[12];

    float* y    = (float*)d_out;            // [B*L, D]
    float* attn = (float*)d_out + kNE;      // [B, L, L]

    // ws: [qrow0 32KB][slotA 67.1MB][slotB][slotC]  => ~201.4MB total
    char* ws = (char*)d_ws;
    float*  qrow0 = (float*)ws;
    __bf16* slotA = (__bf16*)(ws + 32768);
    __bf16* slotB = slotA + 2 * kNE;
    __bf16* slotC = slotB + 2 * kNE;

    // scratch overlays
    __bf16* wTh = (__bf16*)attn;            // q/k/v weightT planes in attn region
    __bf16* wTl = wTh + kNW;                // (dead until logits GEMM writes it)
    __bf16* wToh = slotA;                   // wo weightT planes in slotA
    __bf16* wTol = wToh + kNW;              // (dead after ctx GEMM)

    __bf16 *qh = slotA, *ql = slotA + kNE;  // then attn hi/lo
    __bf16 *kh = slotB, *kl = slotB + kNE;  // then vT hi/lo
    __bf16 *vh = slotC, *vl = slotC + kNE;  // then ctx hi/lo
    __bf16 *ath = slotA, *atl = slotA + kNE;
    __bf16 *vTh = slotB, *vTl = slotB + kNE;
    __bf16 *cth = slotC, *ctl = slotC + kNE;

    const dim3 blk(256);
    const dim3 gW(32, 32);
    const dim3 gT(32, 32, 8);
    const dim3 gProj(16, 64);
    const dim3 gBat(16, 16, 4);

    // q projection (weightT planes overlay attn region of d_out)
    convert_wT<<<gW, blk, 0, stream>>>(wq_w, wTh, wTl);
    gemm_hl<true, true, false, true><<<gProj, blk, 0, stream>>>(
        q_in, nullptr, nullptr, wTh, wTl, wq_b, nullptr, qh, ql,
        8192, 2048, 2048, 0, 0, 0, 1.0f);
    copy_qrow0<<<dim3(32), blk, 0, stream>>>(qh, ql, qrow0);

    // k projection
    convert_wT<<<gW, blk, 0, stream>>>(wk_w, wTh, wTl);
    gemm_hl<true, true, false, true><<<gProj, blk, 0, stream>>>(
        k_in, nullptr, nullptr, wTh, wTl, wk_b, nullptr, kh, kl,
        8192, 2048, 2048, 0, 0, 0, 1.0f);

    // v projection
    convert_wT<<<gW, blk, 0, stream>>>(wv_w, wTh, wTl);
    gemm_hl<true, true, false, true><<<gProj, blk, 0, stream>>>(
        v_in, nullptr, nullptr, wTh, wTl, wv_b, nullptr, vh, vl,
        8192, 2048, 2048, 0, 0, 0, 1.0f);

    // logits = q @ k^T * scale -> d_out attn region (fp32)
    gemm_hl<false, false, true, false><<<gBat, blk, 0, stream>>>(
        nullptr, qh, ql, kh, kl, nullptr, attn, nullptr, nullptr,
        2048, 2048, 2048, kSB, kSB, kSB, kScale);

    // softmax in-place + attn hi/lo (overwrites q hi/lo; qrow0 already saved)
    softmax_rows<<<dim3(kB * kL), blk, 0, stream>>>(attn, ath, atl);

    // vT hi/lo (overwrites k hi/lo)
    transpose_hl<<<gT, blk, 0, stream>>>(vh, vl, vTh, vTl);

    // ctx = attn @ v  ->  ctx hi/lo (overwrites v hi/lo)
    gemm_hl<false, false, false, true><<<gBat, blk, 0, stream>>>(
        nullptr, ath, atl, vTh, vTl, nullptr, nullptr, cth, ctl,
        2048, 2048, 2048, kSB, kSB, kSB, 1.0f);

    // out = ctx @ wo + bo -> y region (fp32); wo planes overlay slotA
    convert_wT<<<gW, blk, 0, stream>>>(wo_w, wToh, wTol);
    gemm_hl<false, true, true, false><<<gProj, blk, 0, stream>>>(
        nullptr, cth, ctl, wToh, wTol, wo_b, y, nullptr, nullptr,
        8192, 2048, 2048, 0, 0, 0, 1.0f);

    // y = LN(y + q_proj[b,0,:]) * g + b   (in place)
    resid_ln<<<dim3(kB * kL), blk, 0, stream>>>(y, qrow0, ln_g, ln_b);
}

// Round 6
// 1352.857 us; speedup vs baseline: 3.7385x; 1.2115x over previous
//
#include <hip/hip_runtime.h>
#include <hip/hip_bf16.h>
#include <stdint.h>

// ---------------------------------------------------------------------------
// MultiheadAttention block (B=4, L=2048, D=2048, H=1).
// Round 6: ALL GEMMs plain bf16 1-term MFMA (absmax proven insensitive:
// fp32 round-0 and bf16x3 round-5 both gave exactly 0.015625 -> reference
// noise floor dominates). Residual q[:,0,:] computed EXACTLY in fp32 by a
// dedicated micro-kernel, so the dominant LN input term has zero GEMM error.
// Structure: 128x128 tile, BK=32, 4 waves, mfma_f32_16x16x32_bf16,
// global_load_lds w=16 (validated at 808 TF effective in round 5).
// Template flips allow per-GEMM revert to 3-term if absmax degrades.
// ---------------------------------------------------------------------------

typedef __bf16 bf16x8 __attribute__((ext_vector_type(8)));
typedef __bf16 bf16x4 __attribute__((ext_vector_type(4)));
typedef float  floatx4 __attribute__((ext_vector_type(4)));

constexpr int    kB = 4, kL = 2048, kD = 2048;
constexpr float  kScale = 0.022097086912079608f;  // 1/sqrt(2048)
constexpr float  kEps   = 1e-6f;
constexpr size_t kNE = (size_t)kB * kL * kD;      // 16,777,216
constexpr size_t kNW = (size_t)kD * kD;           // 4,194,304
constexpr long   kSB = 4194304;                   // per-batch stride (L*D == L*L)

__device__ __forceinline__ void gll16(const void* g, void* l) {
    __builtin_amdgcn_global_load_lds(
        (__attribute__((address_space(1))) void*)(void*)g,
        (__attribute__((address_space(3))) void*)l, 16, 0, 0);
}

struct bfpair { __bf16 h, l; };
__device__ __forceinline__ bfpair split_bf16(float x) {
    bfpair p;
    p.h = (__bf16)x;
    p.l = (__bf16)(x - (float)p.h);
    return p;
}

// C = A @ B'^T (*scale, +bias). A: [M,K] fp32 (CONVA) or bf16 hi(/lo) planes.
// B': [N,K] bf16 hi(/lo) planes. Out: fp32 (WF32) and/or bf16 hi (WH) +lo (WLO).
// T3: 3-term split-bf16 (AhBh+AhBl+AlBh); else plain 1-term bf16.
template<bool CONVA, bool BIAS, bool WF32, bool WH, bool WLO, bool T3>
__global__ __launch_bounds__(256)
void gemm_hl(const float* __restrict__ Af,
             const __bf16* __restrict__ Ah, const __bf16* __restrict__ Al,
             const __bf16* __restrict__ Bh, const __bf16* __restrict__ Bl,
             const float* __restrict__ bias,
             float* __restrict__ Cf, __bf16* __restrict__ Ch, __bf16* __restrict__ Cl,
             int M, int N, int K, long sA, long sB, long sC, float scale)
{
    __shared__ __bf16 smem[(T3 ? 4 : 2) * 128 * 32];
    __bf16* sAh = smem;
    __bf16* sBh = smem + 4096;
    __bf16* sAl = T3 ? smem + 8192  : nullptr;
    __bf16* sBl = T3 ? smem + 12288 : nullptr;

    const int tid  = threadIdx.x;
    const int lane = tid & 63;
    const int wid  = tid >> 6;
    const int wr   = wid >> 1, wc = wid & 1;     // 2x2 waves, 64x64 each
    const int m0   = blockIdx.y * 128, n0 = blockIdx.x * 128;

    const size_t aoff = (size_t)blockIdx.z * sA;
    const size_t boff = (size_t)blockIdx.z * sB;
    const size_t coff = (size_t)blockIdx.z * sC;

    floatx4 acc[4][4];
#pragma unroll
    for (int m = 0; m < 4; ++m)
#pragma unroll
        for (int n = 0; n < 4; ++n) acc[m][n] = floatx4{0.f, 0.f, 0.f, 0.f};

    // fragment read offsets (elements) in [128][32] row-major planes
    const int frow  = lane & 15;
    const int kblk  = lane >> 4;
    const int aBase = (wr * 64 + frow) * 32 + kblk * 8;
    const int bBase = (wc * 64 + frow) * 32 + kblk * 8;
    // global_load_lds per-lane source mapping (16 rows x 64B per instruction)
    const int srow = lane >> 2;
    const int scol = (lane & 3) * 8;

    for (int kt = 0; kt < K; kt += 32) {
        if constexpr (CONVA) {
            // fp32 A rows wid*32..+31 -> bf16 (hi[/lo]) in LDS
#pragma unroll
            for (int j = 0; j < 4; ++j) {
                int flat = j * 64 + lane;
                int r  = wid * 32 + (flat >> 3);
                int kq = (flat & 7) * 4;
                float4 v = *(const float4*)(Af + aoff + (size_t)(m0 + r) * K + kt + kq);
                if constexpr (T3) {
                    bf16x4 hv, lv;
                    bfpair p0 = split_bf16(v.x); hv[0] = p0.h; lv[0] = p0.l;
                    bfpair p1 = split_bf16(v.y); hv[1] = p1.h; lv[1] = p1.l;
                    bfpair p2 = split_bf16(v.z); hv[2] = p2.h; lv[2] = p2.l;
                    bfpair p3 = split_bf16(v.w); hv[3] = p3.h; lv[3] = p3.l;
                    *(bf16x4*)&sAh[r * 32 + kq] = hv;
                    *(bf16x4*)&sAl[r * 32 + kq] = lv;
                } else {
                    bf16x4 hv;
                    hv[0] = (__bf16)v.x; hv[1] = (__bf16)v.y;
                    hv[2] = (__bf16)v.z; hv[3] = (__bf16)v.w;
                    *(bf16x4*)&sAh[r * 32 + kq] = hv;
                }
            }
        } else {
#pragma unroll
            for (int i = 0; i < 2; ++i) {
                int rb = wid * 32 + i * 16;
                gll16(Ah + aoff + (size_t)(m0 + rb + srow) * K + kt + scol, &sAh[rb * 32]);
                if constexpr (T3)
                    gll16(Al + aoff + (size_t)(m0 + rb + srow) * K + kt + scol, &sAl[rb * 32]);
            }
        }
#pragma unroll
        for (int i = 0; i < 2; ++i) {
            int rb = wid * 32 + i * 16;
            gll16(Bh + boff + (size_t)(n0 + rb + srow) * K + kt + scol, &sBh[rb * 32]);
            if constexpr (T3)
                gll16(Bl + boff + (size_t)(n0 + rb + srow) * K + kt + scol, &sBl[rb * 32]);
        }
        __syncthreads();

        bf16x8 ah_[4], bh_[4];
        bf16x8 al_[4], bl_[4];
#pragma unroll
        for (int m = 0; m < 4; ++m) {
            ah_[m] = *(const bf16x8*)&sAh[aBase + m * 512];
            if constexpr (T3) al_[m] = *(const bf16x8*)&sAl[aBase + m * 512];
        }
#pragma unroll
        for (int n = 0; n < 4; ++n) {
            bh_[n] = *(const bf16x8*)&sBh[bBase + n * 512];
            if constexpr (T3) bl_[n] = *(const bf16x8*)&sBl[bBase + n * 512];
        }
#pragma unroll
        for (int m = 0; m < 4; ++m)
#pragma unroll
            for (int n = 0; n < 4; ++n) {
                acc[m][n] = __builtin_amdgcn_mfma_f32_16x16x32_bf16(ah_[m], bh_[n], acc[m][n], 0, 0, 0);
                if constexpr (T3) {
                    acc[m][n] = __builtin_amdgcn_mfma_f32_16x16x32_bf16(ah_[m], bl_[n], acc[m][n], 0, 0, 0);
                    acc[m][n] = __builtin_amdgcn_mfma_f32_16x16x32_bf16(al_[m], bh_[n], acc[m][n], 0, 0, 0);
                }
            }
        __syncthreads();
    }

    // epilogue: C/D layout col = lane&15, row = (lane>>4)*4 + reg
    const int crow0 = m0 + wr * 64 + ((lane >> 4) << 2);
    const int ccol0 = n0 + wc * 64 + (lane & 15);
#pragma unroll
    for (int n = 0; n < 4; ++n) {
        const int col = ccol0 + n * 16;
        const float bv = BIAS ? bias[col] : 0.f;
#pragma unroll
        for (int m = 0; m < 4; ++m)
#pragma unroll
            for (int j = 0; j < 4; ++j) {
                const size_t idx = coff + (size_t)(crow0 + m * 16 + j) * N + col;
                const float x = acc[m][n][j] * scale + bv;
                if constexpr (WF32) Cf[idx] = x;
                if constexpr (WH) {
                    if constexpr (WLO) {
                        bfpair p = split_bf16(x);
                        Ch[idx] = p.h; Cl[idx] = p.l;
                    } else {
                        Ch[idx] = (__bf16)x;
                    }
                }
            }
    }
}

// W[K=2048][N=2048] fp32 -> WT [N][K] bf16 (64x64 LDS tile transpose), hi only
__global__ __launch_bounds__(256)
void convert_wT(const float* __restrict__ w, __bf16* __restrict__ th)
{
    __shared__ float t[64][65];
    const int tid = threadIdx.x;
    const int r0 = blockIdx.y * 64, c0 = blockIdx.x * 64;
#pragma unroll
    for (int i = 0; i < 4; ++i) {
        int flat = i * 256 + tid;
        int r = flat >> 4, c4 = (flat & 15) * 4;
        float4 v = *(const float4*)(w + (size_t)(r0 + r) * kD + c0 + c4);
        t[r][c4 + 0] = v.x; t[r][c4 + 1] = v.y; t[r][c4 + 2] = v.z; t[r][c4 + 3] = v.w;
    }
    __syncthreads();
#pragma unroll
    for (int i = 0; i < 4; ++i) {
        int flat = i * 256 + tid;
        int c = flat >> 4, r4 = (flat & 15) * 4;
        bf16x4 hv;
#pragma unroll
        for (int j = 0; j < 4; ++j) hv[j] = (__bf16)t[r4 + j][c];
        *(bf16x4*)&th[(size_t)(c0 + c) * kD + r0 + r4] = hv;
    }
}

// per-batch transpose: v[b][l][d] -> vT[b][d][l] (bf16, hi plane only)
__global__ __launch_bounds__(256)
void transpose_hl(const __bf16* __restrict__ src, __bf16* __restrict__ dst)
{
    __shared__ __bf16 t[64][73];   // 73: breaks pow-2 column stride
    const __bf16* s = src + (size_t)blockIdx.z * kSB;
    __bf16*       d = dst + (size_t)blockIdx.z * kSB;
    const int tid = threadIdx.x;
    const int r0 = blockIdx.y * 64, c0 = blockIdx.x * 64;
#pragma unroll
    for (int i = 0; i < 2; ++i) {
        int flat = i * 256 + tid;
        int r = flat >> 3, c8 = (flat & 7) * 8;
        bf16x8 v = *(const bf16x8*)&s[(size_t)(r0 + r) * kD + c0 + c8];
#pragma unroll
        for (int j = 0; j < 8; ++j) t[r][c8 + j] = v[j];
    }
    __syncthreads();
#pragma unroll
    for (int i = 0; i < 2; ++i) {
        int flat = i * 256 + tid;
        int c = flat >> 3, r8 = (flat & 7) * 8;
        bf16x8 v;
#pragma unroll
        for (int j = 0; j < 8; ++j) v[j] = t[r8 + j][c];
        *(bf16x8*)&d[(size_t)(c0 + c) * kL + r0 + r8] = v;
    }
}

// in-place row softmax + bf16 output plane. One block per row.
__global__ __launch_bounds__(256)
void softmax_rows(float* __restrict__ attn, __bf16* __restrict__ oh)
{
    const size_t base = (size_t)blockIdx.x * kL;
    const int tid = threadIdx.x, lane = tid & 63, wid = tid >> 6;

    float4 v0 = *(const float4*)(attn + base + tid * 8);
    float4 v1 = *(const float4*)(attn + base + tid * 8 + 4);
    float x[8] = {v0.x, v0.y, v0.z, v0.w, v1.x, v1.y, v1.z, v1.w};

    float m = x[0];
#pragma unroll
    for (int i = 1; i < 8; ++i) m = fmaxf(m, x[i]);
#pragma unroll
    for (int o = 32; o > 0; o >>= 1) m = fmaxf(m, __shfl_xor(m, o));

    __shared__ float rb[8];
    if (lane == 0) rb[wid] = m;
    __syncthreads();
    m = fmaxf(fmaxf(rb[0], rb[1]), fmaxf(rb[2], rb[3]));

    float s = 0.f;
#pragma unroll
    for (int i = 0; i < 8; ++i) { x[i] = __expf(x[i] - m); s += x[i]; }
#pragma unroll
    for (int o = 32; o > 0; o >>= 1) s += __shfl_xor(s, o);
    if (lane == 0) rb[4 + wid] = s;
    __syncthreads();
    s = rb[4] + rb[5] + rb[6] + rb[7];

    const float inv = 1.0f / s;
    bf16x8 hv;
#pragma unroll
    for (int i = 0; i < 8; ++i) {
        x[i] *= inv;
        hv[i] = (__bf16)x[i];
    }
    float4 o0 = {x[0], x[1], x[2], x[3]};
    float4 o1 = {x[4], x[5], x[6], x[7]};
    *(float4*)(attn + base + tid * 8)     = o0;
    *(float4*)(attn + base + tid * 8 + 4) = o1;
    *(bf16x8*)&oh[base + tid * 8] = hv;
}

// Exact fp32 q-projection of row 0 of each batch: q0[b][d] = q_in[b,0,:]@Wq[:,d]+bq[d]
__global__ __launch_bounds__(256)
void qrow0_exact(const float* __restrict__ qin, const float* __restrict__ w,
                 const float* __restrict__ bias, float* __restrict__ q0)
{
    const int idx = blockIdx.x * 256 + threadIdx.x;   // 0..8191 (32 blocks)
    const int b = idx >> 11, d = idx & 2047;
    const float* qr = qin + (size_t)b * kL * kD;      // row 0 of batch b
    float a0 = 0.f, a1 = 0.f, a2 = 0.f, a3 = 0.f;
    for (int k = 0; k < kD; k += 4) {
        a0 = fmaf(qr[k + 0], w[(size_t)(k + 0) * kD + d], a0);
        a1 = fmaf(qr[k + 1], w[(size_t)(k + 1) * kD + d], a1);
        a2 = fmaf(qr[k + 2], w[(size_t)(k + 2) * kD + d], a2);
        a3 = fmaf(qr[k + 3], w[(size_t)(k + 3) * kD + d], a3);
    }
    q0[idx] = ((a0 + a1) + (a2 + a3)) + bias[d];
}

// in-place: y = LN(y + qrow0[b]) * g + b
__global__ __launch_bounds__(256)
void resid_ln(float* __restrict__ y, const float* __restrict__ q0,
              const float* __restrict__ g, const float* __restrict__ bet)
{
    const int row = blockIdx.x;
    const int b = row >> 11;
    const size_t ob = (size_t)row * kD;
    const int tid = threadIdx.x, lane = tid & 63, wid = tid >> 6;

    float4 a0 = *(const float4*)(y + ob + tid * 8);
    float4 a1 = *(const float4*)(y + ob + tid * 8 + 4);
    float4 q0v = *(const float4*)(q0 + b * 2048 + tid * 8);
    float4 q1v = *(const float4*)(q0 + b * 2048 + tid * 8 + 4);
    float x[8] = {a0.x + q0v.x, a0.y + q0v.y, a0.z + q0v.z, a0.w + q0v.w,
                  a1.x + q1v.x, a1.y + q1v.y, a1.z + q1v.z, a1.w + q1v.w};

    float s = 0.f, ss = 0.f;
#pragma unroll
    for (int i = 0; i < 8; ++i) { s += x[i]; ss += x[i] * x[i]; }
#pragma unroll
    for (int o = 32; o > 0; o >>= 1) { s += __shfl_xor(s, o); ss += __shfl_xor(ss, o); }
    __shared__ float rb[16];
    if (lane == 0) { rb[wid] = s; rb[8 + wid] = ss; }
    __syncthreads();
    s  = rb[0] + rb[1] + rb[2] + rb[3];
    ss = rb[8] + rb[9] + rb[10] + rb[11];

    const float mu  = s * (1.0f / kD);
    const float var = ss * (1.0f / kD) - mu * mu;
    const float rs  = rsqrtf(var + kEps);

    float4 g0 = *(const float4*)(g + tid * 8);
    float4 g1 = *(const float4*)(g + tid * 8 + 4);
    float4 b0 = *(const float4*)(bet + tid * 8);
    float4 b1 = *(const float4*)(bet + tid * 8 + 4);

    float4 o0, o1;
    o0.x = (x[0] - mu) * rs * g0.x + b0.x;
    o0.y = (x[1] - mu) * rs * g0.y + b0.y;
    o0.z = (x[2] - mu) * rs * g0.z + b0.z;
    o0.w = (x[3] - mu) * rs * g0.w + b0.w;
    o1.x = (x[4] - mu) * rs * g1.x + b1.x;
    o1.y = (x[5] - mu) * rs * g1.y + b1.y;
    o1.z = (x[6] - mu) * rs * g1.z + b1.z;
    o1.w = (x[7] - mu) * rs * g1.w + b1.w;
    *(float4*)(y + ob + tid * 8)     = o0;
    *(float4*)(y + ob + tid * 8 + 4) = o1;
}

extern "C" void kernel_launch(void* const* d_in, const int* in_sizes, int n_in,
                              void* d_out, int out_size, void* d_ws, size_t ws_size,
                              hipStream_t stream)
{
    (void)in_sizes; (void)n_in; (void)out_size; (void)ws_size;

    const float* q_in = (const float*)d_in[0];
    const float* k_in = (const float*)d_in[1];
    const float* v_in = (const float*)d_in[2];
    const float* wq_w = (const float*)d_in[3];
    const float* wq_b = (const float*)d_in[4];
    const float* wk_w = (const float*)d_in[5];
    const float* wk_b = (const float*)d_in[6];
    const float* wv_w = (const float*)d_in[7];
    const float* wv_b = (const float*)d_in[8];
    const float* wo_w = (const float*)d_in[9];
    const float* wo_b = (const float*)d_in[10];
    const float* ln_g = (const float*)d_in[11];
    const float* ln_b = (const float*)d_in[12];

    float* y    = (float*)d_out;            // [B*L, D]
    float* attn = (float*)d_out + kNE;      // [B, L, L]

    // ws: [qrow0 32KB][slotA][slotB][slotC] (each kNE bf16 = 33.5MB) => ~101MB
    char* ws = (char*)d_ws;
    float*  qrow0 = (float*)ws;
    __bf16* slotA = (__bf16*)(ws + 32768);  // q hi -> attn hi -> woT hi
    __bf16* slotB = slotA + kNE;            // k hi -> vT hi
    __bf16* slotC = slotB + kNE;            // v hi -> ctx hi

    __bf16* wTh  = (__bf16*)attn;           // q/k/v weightT (dead until logits)
    __bf16* qh   = slotA;
    __bf16* kh   = slotB;
    __bf16* vh   = slotC;
    __bf16* ath  = slotA;                   // after softmax (qh dead)
    __bf16* vTh  = slotB;                   // after transpose (kh dead)
    __bf16* cth  = slotC;                   // after PV (vh dead)
    __bf16* wToh = slotA;                   // after PV (ath dead)

    const dim3 blk(256);
    const dim3 gW(32, 32);
    const dim3 gT(32, 32, 4);
    const dim3 gProj(16, 64);
    const dim3 gBat(16, 16, 4);

    // exact fp32 residual row (independent of projections)
    qrow0_exact<<<dim3(32), blk, 0, stream>>>(q_in, wq_w, wq_b, qrow0);

    // q projection (1-term bf16)
    convert_wT<<<gW, blk, 0, stream>>>(wq_w, wTh);
    gemm_hl<true, true, false, true, false, false><<<gProj, blk, 0, stream>>>(
        q_in, nullptr, nullptr, wTh, nullptr, wq_b, nullptr, qh, nullptr,
        8192, 2048, 2048, 0, 0, 0, 1.0f);

    // k projection
    convert_wT<<<gW, blk, 0, stream>>>(wk_w, wTh);
    gemm_hl<true, true, false, true, false, false><<<gProj, blk, 0, stream>>>(
        k_in, nullptr, nullptr, wTh, nullptr, wk_b, nullptr, kh, nullptr,
        8192, 2048, 2048, 0, 0, 0, 1.0f);

    // v projection
    convert_wT<<<gW, blk, 0, stream>>>(wv_w, wTh);
    gemm_hl<true, true, false, true, false, false><<<gProj, blk, 0, stream>>>(
        v_in, nullptr, nullptr, wTh, nullptr, wv_b, nullptr, vh, nullptr,
        8192, 2048, 2048, 0, 0, 0, 1.0f);

    // logits = q @ k^T * scale -> d_out attn region (fp32)
    gemm_hl<false, false, true, false, false, false><<<gBat, blk, 0, stream>>>(
        nullptr, qh, nullptr, kh, nullptr, nullptr, attn, nullptr, nullptr,
        2048, 2048, 2048, kSB, kSB, kSB, kScale);

    // softmax in-place + attn bf16 (overwrites qh; qrow0 independent)
    softmax_rows<<<dim3(kB * kL), blk, 0, stream>>>(attn, ath);

    // vT (overwrites kh)
    transpose_hl<<<gT, blk, 0, stream>>>(vh, vTh);

    // ctx = attn @ v (overwrites vh)
    gemm_hl<false, false, false, true, false, false><<<gBat, blk, 0, stream>>>(
        nullptr, ath, nullptr, vTh, nullptr, nullptr, nullptr, cth, nullptr,
        2048, 2048, 2048, kSB, kSB, kSB, 1.0f);

    // out = ctx @ wo + bo -> y (fp32); woT overlays slotA (ath dead)
    convert_wT<<<gW, blk, 0, stream>>>(wo_w, wToh);
    gemm_hl<false, true, true, false, false, false><<<gProj, blk, 0, stream>>>(
        nullptr, cth, nullptr, wToh, nullptr, wo_b, y, nullptr, nullptr,
        8192, 2048, 2048, 0, 0, 0, 1.0f);

    // y = LN(y + qrow0[b]) * g + b   (in place)
    resid_ln<<<dim3(kB * kL), blk, 0, stream>>>(y, qrow0, ln_g, ln_b);
}